// Round 7
// baseline (106.974 us; speedup 1.0000x reference)
//
#include <hip/hip_runtime.h>
#include <math.h>

#define BATCH 8
#define S 512
#define SS (S * S)          // 262144
#define KMAX 16
#define EMPTY_DD 361.1f     // EMPTY_DIST - distance_thre(=1)
#define SENT 1e9f

// ws int layout (NO pre-zeroing needed: every slot is written before read;
// kernel boundary gives K1->K2 visibility; accumulators zeroed by K1 blk0.
// NO fences / NO release stores anywhere — R3/R5 showed per-block release
// publication costs ~33 µs (L2 writeback per block). Cross-block finale uses
// RELAXED atomics only (coherence-point ops, no cache maintenance), ordered
// before the ticket by a plain s_waitcnt vmcnt(0)):
// [0..256)       cnt1[blk1]   blk1 in [0,256): 32 K1-blocks per image
// [256..4352)    pts[blk1*16 + k]  packed y*512+x (image-local)
// f[7424..7432)  acc_lsum[8]  (atomicAdd)
// f[7432..7440)  acc_gsum[8]  (atomicAdd)
// [7440..7448)   acc_lmax[8]  uint bit-pattern (atomicMax; values >= 0)
// [7448]         ticket
#define PTS_OFF  256
#define ACC_L    7424
#define ACC_G    7432
#define ACC_M    7440
#define TICKET   7448

// ---- K1: find highlight points, atomic-free (per-block private slots) ----
__global__ __launch_bounds__(256) void k_points(const float* __restrict__ ptl,
                                                int* __restrict__ wsi) {
    int tid = threadIdx.x;
    int blk = blockIdx.x;        // 256 blocks: 32 per image, 16 rows each
    int b  = blk >> 5;
    int rg = blk & 31;

    __shared__ int l_cnt;
    __shared__ int l_fnd[KMAX];
    if (tid == 0) l_cnt = 0;
    if (blk == 0 && tid < 25) wsi[ACC_L + tid] = 0;   // zero accumulators+ticket
    __syncthreads();

    const float4* p4 = (const float4*)(ptl + b * SS + rg * (16 * S));
#pragma unroll
    for (int q = 0; q < 8; q++) {
        float4 v = p4[q * 256 + tid];            // lane-consecutive float4
        if (v.x + v.y + v.z + v.w != 0.0f) {     // labels are >= 0
            int i0 = rg * (16 * S) + (q * 256 + tid) * 4;
            float c[4] = {v.x, v.y, v.z, v.w};
#pragma unroll
            for (int j = 0; j < 4; j++) {
                if (c[j] != 0.0f) {
                    int slot = atomicAdd(&l_cnt, 1);   // shared-mem atomic only
                    if (slot < KMAX) l_fnd[slot] = i0 + j;
                }
            }
        }
    }
    __syncthreads();
    int lcnt = l_cnt; if (lcnt > KMAX) lcnt = KMAX;
    if (tid == 0) wsi[blk] = lcnt;
    if (tid < lcnt) wsi[PTS_OFF + blk * KMAX + tid] = l_fnd[tid];
}

// ---- K2: gather points + fused Sobel + distance + atomic finale ----
__global__ __launch_bounds__(256, 4) void k_main(const float* __restrict__ pred,
                                                 const float* __restrict__ ori,
                                                 int* __restrict__ wsi,
                                                 float* __restrict__ wsf,
                                                 float* __restrict__ out) {
    int tid = threadIdx.x;
    int blk = blockIdx.x;        // 1024 blocks: 128 per image, 4 rows each
    int b  = blk >> 7;
    int rg = blk & 127;
    int wave = tid >> 6;         // 0..3, one row per wave
    int lane = tid & 63;

    __shared__ int l_list[KMAX];
    __shared__ int l_total;
    __shared__ float sm[4][3];
    __shared__ int l_last;

    // ---- gather this image's points from the 32 K1-block lists (wave 0) ----
    if (wave == 0) {
        int cj = 0;
        if (lane < 32) cj = wsi[(b << 5) + lane];
        int pre = cj;
#pragma unroll
        for (int d = 1; d < 32; d <<= 1) {
            int t = __shfl_up(pre, d, 64);
            if (lane >= d && lane < 32) pre += t;
        }
        if (lane == 31) l_total = (pre > KMAX) ? KMAX : pre;
        int off = pre - cj;      // exclusive prefix
        if (lane < 32) {
            for (int k = 0; k < cj; k++) {
                if (off + k < KMAX)
                    l_list[off + k] = wsi[PTS_OFF + ((b << 5) + lane) * KMAX + k];
            }
        }
    }
    __syncthreads();

    int cnt = l_total;
    bool has = cnt > 0;
    float pyk[KMAX], pxk[KMAX];
#pragma unroll
    for (int k = 0; k < KMAX; k++) {
        if (k < cnt) {
            int pk = l_list[k];
            pyk[k] = (float)(pk >> 9);
            pxk[k] = (float)(pk & 511);
        } else { pyk[k] = SENT; pxk[k] = SENT; }
    }

    const float* pb = pred + b * SS;
    const float* ob = ori + b * SS;
    int y = rg * 4 + wave;       // wave-uniform row
    int x0 = lane << 3;

    const float4* prow = (const float4*)(pb + y * S + x0);
    float4 pA = prow[0], pB = prow[1];

    // ---- Sobel for own row ----
    float gsum = 0.0f;
    if (y > 0 && y < S - 1) {
        float r[3][10];
#pragma unroll
        for (int ri = 0; ri < 3; ri++) {
            int yy = y - 1 + ri;
            const float4* pr  = (const float4*)(pb + yy * S + x0);
            const float4* orr = (const float4*)(ob + yy * S + x0);
            float4 p0 = (ri == 1) ? pA : pr[0];
            float4 p1 = (ri == 1) ? pB : pr[1];
            float4 o0 = orr[0], o1 = orr[1];
            r[ri][1] = p0.x * o0.x; r[ri][2] = p0.y * o0.y;
            r[ri][3] = p0.z * o0.z; r[ri][4] = p0.w * o0.w;
            r[ri][5] = p1.x * o1.x; r[ri][6] = p1.y * o1.y;
            r[ri][7] = p1.z * o1.z; r[ri][8] = p1.w * o1.w;
            r[ri][0] = __shfl_up(r[ri][8], 1, 64);    // lane0 value dead (x=0 zeroed)
            r[ri][9] = __shfl_down(r[ri][1], 1, 64);  // lane63 value dead (x=511 zeroed)
        }
#pragma unroll
        for (int j = 0; j < 8; j++) {
            float a00 = r[0][j], a01 = r[0][j + 1], a02 = r[0][j + 2];
            float a10 = r[1][j],                    a12 = r[1][j + 2];
            float a20 = r[2][j], a21 = r[2][j + 1], a22 = r[2][j + 2];
            float g0 = -a00 + a02 - 2.0f * a10 + 2.0f * a12 - a20 + a22;
            float g1 =  a00 + 2.0f * a01 + a02 - a20 - 2.0f * a21 - a22;
            float g2 =  2.0f * a00 + a01 + a10 - a12 - a21 - 2.0f * a22;
            float g3 =  a01 + 2.0f * a02 - a10 + a12 - 2.0f * a20 - a21;
            float gv = fmaxf(fmaxf(fabsf(g0), fabsf(g1)), fmaxf(fabsf(g2), fabsf(g3)));
            bool edge = (lane == 0 && j == 0) || (lane == 63 && j == 7);
            gsum += edge ? 0.0f : gv;
        }
    }

    // ---- distance for own row ----
    float fy = (float)y;
    float fx = (float)x0;
    float m[8];
#pragma unroll
    for (int j = 0; j < 8; j++) m[j] = 1e30f;
#pragma unroll
    for (int k = 0; k < KMAX; k++) {
        float dy = fy - pyk[k];
        float dy2 = dy * dy;
        float dx = fx - pxk[k];
#pragma unroll
        for (int j = 0; j < 8; j++) {
            float d = dx + (float)j;
            m[j] = fminf(m[j], fmaf(d, d, dy2));
        }
    }
    float dd[8];
#pragma unroll
    for (int j = 0; j < 8; j++)
        dd[j] = has ? fmaxf(sqrtf(m[j]) - 1.0f, 0.0f) : EMPTY_DD;

    float lsum = pA.x * dd[0] + pA.y * dd[1] + pA.z * dd[2] + pA.w * dd[3] +
                 pB.x * dd[4] + pB.y * dd[5] + pB.z * dd[6] + pB.w * dd[7];
    float lmax = fmaxf(fmaxf(fmaxf(dd[0], dd[1]), fmaxf(dd[2], dd[3])),
                       fmaxf(fmaxf(dd[4], dd[5]), fmaxf(dd[6], dd[7])));

    // ---- block reduce (4 waves) + relaxed-atomic finale ----
#pragma unroll
    for (int off = 32; off > 0; off >>= 1) {
        lsum += __shfl_down(lsum, off, 64);
        gsum += __shfl_down(gsum, off, 64);
        lmax = fmaxf(lmax, __shfl_down(lmax, off, 64));
    }
    if (lane == 0) { sm[wave][0] = lsum; sm[wave][1] = gsum; sm[wave][2] = lmax; }
    __syncthreads();
    if (tid == 0) {
#pragma unroll
        for (int w = 1; w < 4; w++) {
            lsum += sm[w][0];
            gsum += sm[w][1];
            lmax = fmaxf(lmax, sm[w][2]);
        }
        // relaxed device-scope atomics: act at coherence point, no L2 flush
        atomicAdd(&wsf[ACC_L + b], lsum);
        atomicAdd(&wsf[ACC_G + b], gsum);
        atomicMax((unsigned int*)&wsi[ACC_M + b], __float_as_uint(lmax)); // lmax >= 0
        // order value-atomics before ticket: counted wait, NOT cache maintenance
        asm volatile("s_waitcnt vmcnt(0)" ::: "memory");
        int t = atomicAdd(&wsi[TICKET], 1);
        l_last = (t == 1023) ? 1 : 0;
    }
    __syncthreads();

    // ---- last block only: 8 lanes finalize from the 24 accumulated words ----
    if (l_last && wave == 0) {
        float dl = 0.0f, gl = 0.0f;
        if (lane < BATCH) {
            float ls = __hip_atomic_load(&wsf[ACC_L + lane], __ATOMIC_RELAXED, __HIP_MEMORY_SCOPE_AGENT);
            float gs = __hip_atomic_load(&wsf[ACC_G + lane], __ATOMIC_RELAXED, __HIP_MEMORY_SCOPE_AGENT);
            unsigned mb = __hip_atomic_load((unsigned int*)&wsi[ACC_M + lane], __ATOMIC_RELAXED, __HIP_MEMORY_SCOPE_AGENT);
            dl = ls / __uint_as_float(mb);
            gl = gs;
        }
#pragma unroll
        for (int off = 4; off > 0; off >>= 1) {
            dl += __shfl_down(dl, off, 64);
            gl += __shfl_down(gl, off, 64);
        }
        if (lane == 0) {
            out[0] = dl / (float)(SS * BATCH);
            out[1] = gl / (float)(SS * BATCH);
        }
    }
}

extern "C" void kernel_launch(void* const* d_in, const int* in_sizes, int n_in,
                              void* d_out, int out_size, void* d_ws, size_t ws_size,
                              hipStream_t stream) {
    const float* pred = (const float*)d_in[0];
    const float* ptl  = (const float*)d_in[1];
    const float* ori  = (const float*)d_in[2];
    float* out = (float*)d_out;
    int* wsi = (int*)d_ws;
    float* wsf = (float*)d_ws;

    k_points<<<256, 256, 0, stream>>>(ptl, wsi);
    k_main<<<1024, 256, 0, stream>>>(pred, ori, wsi, wsf, out);
}

// Round 8
// 82.442 us; speedup vs baseline: 1.2976x; 1.2976x over previous
//
#include <hip/hip_runtime.h>
#include <math.h>

#define BATCH 8
#define S 512
#define SS (S * S)          // 262144
#define KMAX 16
#define EMPTY_DD 361.1f     // EMPTY_DIST - distance_thre(=1)
#define SENT 1e9f

// ws int layout (NO pre-zeroing needed: every slot is written by an earlier
// kernel before any later kernel reads it; kernel boundaries give visibility;
// NO device-scope fences/atomics/flags anywhere — R3/R5/R7 each measured
// ~25-35 µs for any per-block cross-XCD publication scheme; a kernel
// boundary costs ~5 µs and is the only cheap device-wide barrier here):
// [0..1024)        cnt1[blk1]  blk1 in [0,1024): 128 K1-blocks/image, 4 rows each
// [1024..17408)    pts[blk1*16 + k]  packed y*512+x (image-local)
// f[17408..17920)  lsum[512]   per-K2-block partials (blk = img*64 + rg)
// f[17920..18432)  gsum[512]
// f[18432..18944)  lmax[512]
#define PTS_OFF  1024
#define LSUM_OFF 17408
#define GSUM_OFF 17920
#define LMAX_OFF 18432

// ---- K1: find highlight points, atomic-free (per-block private slots) ----
// 1024 blocks x 256 thr = 16 waves/CU (4/SIMD) streaming 8 MB.
__global__ __launch_bounds__(256) void k_points(const float* __restrict__ ptl,
                                                int* __restrict__ wsi) {
    int tid = threadIdx.x;
    int blk = blockIdx.x;        // 1024 blocks: 128 per image, 4 rows each
    int b  = blk >> 7;
    int rg = blk & 127;

    __shared__ int l_cnt;
    __shared__ int l_fnd[KMAX];
    if (tid == 0) l_cnt = 0;
    __syncthreads();

    const float4* p4 = (const float4*)(ptl + b * SS + rg * (4 * S));
#pragma unroll
    for (int q = 0; q < 2; q++) {
        float4 v = p4[q * 256 + tid];            // lane-consecutive float4
        if (v.x + v.y + v.z + v.w != 0.0f) {     // labels are >= 0
            int i0 = rg * (4 * S) + (q * 256 + tid) * 4;
            float c[4] = {v.x, v.y, v.z, v.w};
#pragma unroll
            for (int j = 0; j < 4; j++) {
                if (c[j] != 0.0f) {
                    int slot = atomicAdd(&l_cnt, 1);   // shared-mem atomic only
                    if (slot < KMAX) l_fnd[slot] = i0 + j;
                }
            }
        }
    }
    __syncthreads();
    int lcnt = l_cnt; if (lcnt > KMAX) lcnt = KMAX;
    if (tid == 0) wsi[blk] = lcnt;
    if (tid < lcnt) wsi[PTS_OFF + blk * KMAX + tid] = l_fnd[tid];
}

// ---- K2: prefetch rows -> gather points -> distance + Sobel ----
// 512 blocks x 512 thr (8 waves, one row/wave, 8 px/lane).
__global__ __launch_bounds__(512, 4) void k_main(const float* __restrict__ pred,
                                                 const float* __restrict__ ori,
                                                 const int* __restrict__ wsi,
                                                 float* __restrict__ wsf) {
    int tid = threadIdx.x;
    int blk = blockIdx.x;        // 512 blocks: 64 per image, 8 rows each
    int b  = blk >> 6;
    int rg = blk & 63;
    int wave = tid >> 6;         // 0..7, one row per wave
    int lane = tid & 63;

    __shared__ int l_list[KMAX];
    __shared__ int l_total;
    __shared__ float sm[8][3];

    const float* pb = pred + b * SS;
    const float* ob = ori + b * SS;
    int y  = (rg << 3) + wave;   // wave-uniform row
    int x0 = lane << 3;

    // ---- phase 0: issue ALL row loads + build Sobel products BEFORE gather
    // (independent of points; hides HBM/L2 latency under the gather) ----
    const float4* pc = (const float4*)(pb + y * S + x0);
    float4 pA = pc[0], pB = pc[1];

    bool inner = (y > 0 && y < S - 1);
    float r[3][10];
    if (inner) {
        const float4* pu = (const float4*)(pb + (y - 1) * S + x0);
        const float4* pd = (const float4*)(pb + (y + 1) * S + x0);
        const float4* ou = (const float4*)(ob + (y - 1) * S + x0);
        const float4* om = (const float4*)(ob + y * S + x0);
        const float4* od = (const float4*)(ob + (y + 1) * S + x0);
        float4 pu0 = pu[0], pu1 = pu[1], pd0 = pd[0], pd1 = pd[1];
        float4 ou0 = ou[0], ou1 = ou[1], om0 = om[0], om1 = om[1];
        float4 od0 = od[0], od1 = od[1];
        r[0][1] = pu0.x * ou0.x; r[0][2] = pu0.y * ou0.y;
        r[0][3] = pu0.z * ou0.z; r[0][4] = pu0.w * ou0.w;
        r[0][5] = pu1.x * ou1.x; r[0][6] = pu1.y * ou1.y;
        r[0][7] = pu1.z * ou1.z; r[0][8] = pu1.w * ou1.w;
        r[1][1] = pA.x * om0.x;  r[1][2] = pA.y * om0.y;
        r[1][3] = pA.z * om0.z;  r[1][4] = pA.w * om0.w;
        r[1][5] = pB.x * om1.x;  r[1][6] = pB.y * om1.y;
        r[1][7] = pB.z * om1.z;  r[1][8] = pB.w * om1.w;
        r[2][1] = pd0.x * od0.x; r[2][2] = pd0.y * od0.y;
        r[2][3] = pd0.z * od0.z; r[2][4] = pd0.w * od0.w;
        r[2][5] = pd1.x * od1.x; r[2][6] = pd1.y * od1.y;
        r[2][7] = pd1.z * od1.z; r[2][8] = pd1.w * od1.w;
#pragma unroll
        for (int ri = 0; ri < 3; ri++) {
            r[ri][0] = __shfl_up(r[ri][8], 1, 64);    // lane0 value dead (x=0 zeroed)
            r[ri][9] = __shfl_down(r[ri][1], 1, 64);  // lane63 value dead (x=511 zeroed)
        }
    }

    // ---- gather this image's points from its 128 K1-block lists (wave 0) ----
    if (wave == 0) {
        int base = b << 7;       // 128 lists per image, 2 per lane
        int cj0 = wsi[base + 2 * lane];
        int cj1 = wsi[base + 2 * lane + 1];
        int ps = cj0 + cj1;
        int incl = ps;
#pragma unroll
        for (int d = 1; d < 64; d <<= 1) {
            int t = __shfl_up(incl, d, 64);
            if (lane >= d) incl += t;
        }
        if (lane == 63) l_total = (incl > KMAX) ? KMAX : incl;
        int excl = incl - ps;    // exclusive prefix over pairs
        int off0 = excl, off1 = excl + cj0;
        for (int k = 0; k < cj0; k++)
            if (off0 + k < KMAX)
                l_list[off0 + k] = wsi[PTS_OFF + (base + 2 * lane) * KMAX + k];
        for (int k = 0; k < cj1; k++)
            if (off1 + k < KMAX)
                l_list[off1 + k] = wsi[PTS_OFF + (base + 2 * lane + 1) * KMAX + k];
    }
    __syncthreads();

    int cnt = l_total;
    bool has = cnt > 0;
    float pyk[KMAX], pxk[KMAX];
#pragma unroll
    for (int k = 0; k < KMAX; k++) {
        if (k < cnt) {
            int pk = l_list[k];
            pyk[k] = (float)(pk >> 9);
            pxk[k] = (float)(pk & 511);
        } else { pyk[k] = SENT; pxk[k] = SENT; }
    }

    // ---- distance for own row ----
    float fy = (float)y;
    float fx = (float)x0;
    float m[8];
#pragma unroll
    for (int j = 0; j < 8; j++) m[j] = 1e30f;
#pragma unroll
    for (int k = 0; k < KMAX; k++) {
        float dy = fy - pyk[k];
        float dy2 = dy * dy;
        float dx = fx - pxk[k];
#pragma unroll
        for (int j = 0; j < 8; j++) {
            float d = dx + (float)j;
            m[j] = fminf(m[j], fmaf(d, d, dy2));
        }
    }
    float dd[8];
#pragma unroll
    for (int j = 0; j < 8; j++)
        dd[j] = has ? fmaxf(sqrtf(m[j]) - 1.0f, 0.0f) : EMPTY_DD;

    float lsum = pA.x * dd[0] + pA.y * dd[1] + pA.z * dd[2] + pA.w * dd[3] +
                 pB.x * dd[4] + pB.y * dd[5] + pB.z * dd[6] + pB.w * dd[7];
    float lmax = fmaxf(fmaxf(fmaxf(dd[0], dd[1]), fmaxf(dd[2], dd[3])),
                       fmaxf(fmaxf(dd[4], dd[5]), fmaxf(dd[6], dd[7])));

    // ---- Sobel arithmetic from prefetched products ----
    float gsum = 0.0f;
    if (inner) {
#pragma unroll
        for (int j = 0; j < 8; j++) {
            float a00 = r[0][j], a01 = r[0][j + 1], a02 = r[0][j + 2];
            float a10 = r[1][j],                    a12 = r[1][j + 2];
            float a20 = r[2][j], a21 = r[2][j + 1], a22 = r[2][j + 2];
            float g0 = -a00 + a02 - 2.0f * a10 + 2.0f * a12 - a20 + a22;
            float g1 =  a00 + 2.0f * a01 + a02 - a20 - 2.0f * a21 - a22;
            float g2 =  2.0f * a00 + a01 + a10 - a12 - a21 - 2.0f * a22;
            float g3 =  a01 + 2.0f * a02 - a10 + a12 - 2.0f * a20 - a21;
            float gv = fmaxf(fmaxf(fabsf(g0), fabsf(g1)), fmaxf(fabsf(g2), fabsf(g3)));
            bool edge = (lane == 0 && j == 0) || (lane == 63 && j == 7);
            gsum += edge ? 0.0f : gv;
        }
    }

    // ---- block reduce (8 waves) + publish partials (plain stores) ----
#pragma unroll
    for (int off = 32; off > 0; off >>= 1) {
        lsum += __shfl_down(lsum, off, 64);
        gsum += __shfl_down(gsum, off, 64);
        lmax = fmaxf(lmax, __shfl_down(lmax, off, 64));
    }
    if (lane == 0) { sm[wave][0] = lsum; sm[wave][1] = gsum; sm[wave][2] = lmax; }
    __syncthreads();
    if (tid == 0) {
#pragma unroll
        for (int w = 1; w < 8; w++) {
            lsum += sm[w][0];
            gsum += sm[w][1];
            lmax = fmaxf(lmax, sm[w][2]);
        }
        wsf[LSUM_OFF + blk] = lsum;
        wsf[GSUM_OFF + blk] = gsum;
        wsf[LMAX_OFF + blk] = lmax;
    }
}

// ---- K3: final reduction over 512 partials (wave w = image w) ----
__global__ __launch_bounds__(512) void k_final(const float* __restrict__ wsf,
                                               float* __restrict__ out) {
    int tid = threadIdx.x;
    int lane = tid & 63;
    int w = tid >> 6;            // 0..7 = image; its 64 partials at [w*64..w*64+63]

    __shared__ float smf[8][3];

    int idx = (w << 6) + lane;
    float ls = wsf[LSUM_OFF + idx];
    float gs = wsf[GSUM_OFF + idx];
    float lm = wsf[LMAX_OFF + idx];
#pragma unroll
    for (int off = 32; off > 0; off >>= 1) {
        ls += __shfl_down(ls, off, 64);
        gs += __shfl_down(gs, off, 64);
        lm = fmaxf(lm, __shfl_down(lm, off, 64));
    }
    if (lane == 0) { smf[w][0] = ls; smf[w][1] = gs; smf[w][2] = lm; }
    __syncthreads();
    if (tid == 0) {
        float dl = 0.0f, gl = 0.0f;
#pragma unroll
        for (int img = 0; img < BATCH; img++) {
            dl += smf[img][0] / smf[img][2];
            gl += smf[img][1];
        }
        out[0] = dl / (float)(SS * BATCH);
        out[1] = gl / (float)(SS * BATCH);
    }
}

extern "C" void kernel_launch(void* const* d_in, const int* in_sizes, int n_in,
                              void* d_out, int out_size, void* d_ws, size_t ws_size,
                              hipStream_t stream) {
    const float* pred = (const float*)d_in[0];
    const float* ptl  = (const float*)d_in[1];
    const float* ori  = (const float*)d_in[2];
    float* out = (float*)d_out;
    int* wsi = (int*)d_ws;
    float* wsf = (float*)d_ws;

    k_points<<<1024, 256, 0, stream>>>(ptl, wsi);
    k_main<<<512, 512, 0, stream>>>(pred, ori, wsi, wsf);
    k_final<<<1, 512, 0, stream>>>(wsf, out);
}

// Round 9
// 81.280 us; speedup vs baseline: 1.3161x; 1.0143x over previous
//
#include <hip/hip_runtime.h>
#include <math.h>

#define BATCH 8
#define S 512
#define SS (S * S)          // 262144
#define KMAX 16
#define EMPTY_DD 361.1f     // EMPTY_DIST - distance_thre(=1)
#define SENT 1e9f

// ws int layout (NO pre-zeroing needed: every slot is written by an earlier
// kernel before any later kernel reads it; kernel boundaries give visibility;
// NO device-scope fences/atomics/flags anywhere — R3/R5/R7 each measured
// ~25-35 µs for any per-block cross-XCD publication scheme; a kernel
// boundary costs ~5 µs and is the only cheap device-wide barrier here):
// [0..1024)        cnt1[blk1]  blk1 in [0,1024): 128 K1-blocks/image, 4 rows each
// [1024..17408)    pts[blk1*16 + k]  packed y*512+x (image-local)
// f[17408..18432)  lsum[1024]  per-K2-block partials (blk = img*128 + rg)
// f[18432..19456)  gsum[1024]
// f[19456..20480)  lmax[1024]
#define PTS_OFF  1024
#define LSUM_OFF 17408
#define GSUM_OFF 18432
#define LMAX_OFF 19456

// ---- K1: find highlight points, atomic-free (per-block private slots) ----
// 1024 blocks x 256 thr = 16 waves/CU (4/SIMD) streaming 8 MB.
__global__ __launch_bounds__(256) void k_points(const float* __restrict__ ptl,
                                                int* __restrict__ wsi) {
    int tid = threadIdx.x;
    int blk = blockIdx.x;        // 1024 blocks: 128 per image, 4 rows each
    int b  = blk >> 7;
    int rg = blk & 127;

    __shared__ int l_cnt;
    __shared__ int l_fnd[KMAX];
    if (tid == 0) l_cnt = 0;
    __syncthreads();

    const float4* p4 = (const float4*)(ptl + b * SS + rg * (4 * S));
#pragma unroll
    for (int q = 0; q < 2; q++) {
        float4 v = p4[q * 256 + tid];            // lane-consecutive float4
        if (v.x + v.y + v.z + v.w != 0.0f) {     // labels are >= 0
            int i0 = rg * (4 * S) + (q * 256 + tid) * 4;
            float c[4] = {v.x, v.y, v.z, v.w};
#pragma unroll
            for (int j = 0; j < 4; j++) {
                if (c[j] != 0.0f) {
                    int slot = atomicAdd(&l_cnt, 1);   // shared-mem atomic only
                    if (slot < KMAX) l_fnd[slot] = i0 + j;
                }
            }
        }
    }
    __syncthreads();
    int lcnt = l_cnt; if (lcnt > KMAX) lcnt = KMAX;
    if (tid == 0) wsi[blk] = lcnt;
    if (tid < lcnt) wsi[PTS_OFF + blk * KMAX + tid] = l_fnd[tid];
}

// ---- K2: prefetch rows -> gather points -> distance + Sobel ----
// 1024 blocks x 256 thr (R4's proven shape): 4 waves, one full row/wave.
__global__ __launch_bounds__(256, 4) void k_main(const float* __restrict__ pred,
                                                 const float* __restrict__ ori,
                                                 const int* __restrict__ wsi,
                                                 float* __restrict__ wsf) {
    int tid = threadIdx.x;
    int blk = blockIdx.x;        // 1024 blocks: 128 per image, 4 rows each
    int b  = blk >> 7;
    int rg = blk & 127;
    int wave = tid >> 6;         // 0..3, one row per wave
    int lane = tid & 63;

    __shared__ int l_list[KMAX];
    __shared__ int l_total;
    __shared__ float sm[4][3];

    const float* pb = pred + b * SS;
    const float* ob = ori + b * SS;
    int y  = (rg << 2) + wave;   // wave-uniform row
    int x0 = lane << 3;

    // ---- phase 0: issue ALL row loads + build Sobel products BEFORE gather
    // (independent of points; hides HBM/L2 latency under the gather) ----
    const float4* pc = (const float4*)(pb + y * S + x0);
    float4 pA = pc[0], pB = pc[1];

    bool inner = (y > 0 && y < S - 1);
    float r[3][10];
    if (inner) {
        const float4* pu = (const float4*)(pb + (y - 1) * S + x0);
        const float4* pd = (const float4*)(pb + (y + 1) * S + x0);
        const float4* ou = (const float4*)(ob + (y - 1) * S + x0);
        const float4* om = (const float4*)(ob + y * S + x0);
        const float4* od = (const float4*)(ob + (y + 1) * S + x0);
        float4 pu0 = pu[0], pu1 = pu[1], pd0 = pd[0], pd1 = pd[1];
        float4 ou0 = ou[0], ou1 = ou[1], om0 = om[0], om1 = om[1];
        float4 od0 = od[0], od1 = od[1];
        r[0][1] = pu0.x * ou0.x; r[0][2] = pu0.y * ou0.y;
        r[0][3] = pu0.z * ou0.z; r[0][4] = pu0.w * ou0.w;
        r[0][5] = pu1.x * ou1.x; r[0][6] = pu1.y * ou1.y;
        r[0][7] = pu1.z * ou1.z; r[0][8] = pu1.w * ou1.w;
        r[1][1] = pA.x * om0.x;  r[1][2] = pA.y * om0.y;
        r[1][3] = pA.z * om0.z;  r[1][4] = pA.w * om0.w;
        r[1][5] = pB.x * om1.x;  r[1][6] = pB.y * om1.y;
        r[1][7] = pB.z * om1.z;  r[1][8] = pB.w * om1.w;
        r[2][1] = pd0.x * od0.x; r[2][2] = pd0.y * od0.y;
        r[2][3] = pd0.z * od0.z; r[2][4] = pd0.w * od0.w;
        r[2][5] = pd1.x * od1.x; r[2][6] = pd1.y * od1.y;
        r[2][7] = pd1.z * od1.z; r[2][8] = pd1.w * od1.w;
#pragma unroll
        for (int ri = 0; ri < 3; ri++) {
            r[ri][0] = __shfl_up(r[ri][8], 1, 64);    // lane0 value dead (x=0 zeroed)
            r[ri][9] = __shfl_down(r[ri][1], 1, 64);  // lane63 value dead (x=511 zeroed)
        }
    }

    // ---- gather this image's points from its 128 K1-block lists (wave 0) ----
    if (wave == 0) {
        int base = b << 7;       // 128 lists per image, 2 per lane
        int cj0 = wsi[base + 2 * lane];
        int cj1 = wsi[base + 2 * lane + 1];
        int ps = cj0 + cj1;
        int incl = ps;
#pragma unroll
        for (int d = 1; d < 64; d <<= 1) {
            int t = __shfl_up(incl, d, 64);
            if (lane >= d) incl += t;
        }
        if (lane == 63) l_total = (incl > KMAX) ? KMAX : incl;
        int excl = incl - ps;    // exclusive prefix over pairs
        int off0 = excl, off1 = excl + cj0;
        for (int k = 0; k < cj0; k++)
            if (off0 + k < KMAX)
                l_list[off0 + k] = wsi[PTS_OFF + (base + 2 * lane) * KMAX + k];
        for (int k = 0; k < cj1; k++)
            if (off1 + k < KMAX)
                l_list[off1 + k] = wsi[PTS_OFF + (base + 2 * lane + 1) * KMAX + k];
    }
    __syncthreads();

    int cnt = l_total;
    bool has = cnt > 0;
    float pyk[KMAX], pxk[KMAX];
#pragma unroll
    for (int k = 0; k < KMAX; k++) {
        if (k < cnt) {
            int pk = l_list[k];
            pyk[k] = (float)(pk >> 9);
            pxk[k] = (float)(pk & 511);
        } else { pyk[k] = SENT; pxk[k] = SENT; }
    }

    // ---- distance for own row ----
    float fy = (float)y;
    float fx = (float)x0;
    float m[8];
#pragma unroll
    for (int j = 0; j < 8; j++) m[j] = 1e30f;
#pragma unroll
    for (int k = 0; k < KMAX; k++) {
        float dy = fy - pyk[k];
        float dy2 = dy * dy;
        float dx = fx - pxk[k];
#pragma unroll
        for (int j = 0; j < 8; j++) {
            float d = dx + (float)j;
            m[j] = fminf(m[j], fmaf(d, d, dy2));
        }
    }
    float dd[8];
#pragma unroll
    for (int j = 0; j < 8; j++)
        dd[j] = has ? fmaxf(sqrtf(m[j]) - 1.0f, 0.0f) : EMPTY_DD;

    float lsum = pA.x * dd[0] + pA.y * dd[1] + pA.z * dd[2] + pA.w * dd[3] +
                 pB.x * dd[4] + pB.y * dd[5] + pB.z * dd[6] + pB.w * dd[7];
    float lmax = fmaxf(fmaxf(fmaxf(dd[0], dd[1]), fmaxf(dd[2], dd[3])),
                       fmaxf(fmaxf(dd[4], dd[5]), fmaxf(dd[6], dd[7])));

    // ---- Sobel arithmetic from prefetched products ----
    float gsum = 0.0f;
    if (inner) {
#pragma unroll
        for (int j = 0; j < 8; j++) {
            float a00 = r[0][j], a01 = r[0][j + 1], a02 = r[0][j + 2];
            float a10 = r[1][j],                    a12 = r[1][j + 2];
            float a20 = r[2][j], a21 = r[2][j + 1], a22 = r[2][j + 2];
            float g0 = -a00 + a02 - 2.0f * a10 + 2.0f * a12 - a20 + a22;
            float g1 =  a00 + 2.0f * a01 + a02 - a20 - 2.0f * a21 - a22;
            float g2 =  2.0f * a00 + a01 + a10 - a12 - a21 - 2.0f * a22;
            float g3 =  a01 + 2.0f * a02 - a10 + a12 - 2.0f * a20 - a21;
            float gv = fmaxf(fmaxf(fabsf(g0), fabsf(g1)), fmaxf(fabsf(g2), fabsf(g3)));
            bool edge = (lane == 0 && j == 0) || (lane == 63 && j == 7);
            gsum += edge ? 0.0f : gv;
        }
    }

    // ---- block reduce (4 waves) + publish partials (plain stores) ----
#pragma unroll
    for (int off = 32; off > 0; off >>= 1) {
        lsum += __shfl_down(lsum, off, 64);
        gsum += __shfl_down(gsum, off, 64);
        lmax = fmaxf(lmax, __shfl_down(lmax, off, 64));
    }
    if (lane == 0) { sm[wave][0] = lsum; sm[wave][1] = gsum; sm[wave][2] = lmax; }
    __syncthreads();
    if (tid == 0) {
#pragma unroll
        for (int w = 1; w < 4; w++) {
            lsum += sm[w][0];
            gsum += sm[w][1];
            lmax = fmaxf(lmax, sm[w][2]);
        }
        wsf[LSUM_OFF + blk] = lsum;
        wsf[GSUM_OFF + blk] = gsum;
        wsf[LMAX_OFF + blk] = lmax;
    }
}

// ---- K3: final reduction over 1024 partials ----
__global__ __launch_bounds__(1024) void k_final(const float* __restrict__ wsf,
                                                float* __restrict__ out) {
    int tid = threadIdx.x;
    int lane = tid & 63;
    int w = tid >> 6;            // 0..15; image = w>>1 (partials laid out [img][128])

    __shared__ float smf[16][3];

    float ls = wsf[LSUM_OFF + tid];
    float gs = wsf[GSUM_OFF + tid];
    float lm = wsf[LMAX_OFF + tid];
#pragma unroll
    for (int off = 32; off > 0; off >>= 1) {
        ls += __shfl_down(ls, off, 64);
        gs += __shfl_down(gs, off, 64);
        lm = fmaxf(lm, __shfl_down(lm, off, 64));
    }
    if (lane == 0) { smf[w][0] = ls; smf[w][1] = gs; smf[w][2] = lm; }
    __syncthreads();
    if (tid == 0) {
        float dl = 0.0f, gl = 0.0f;
#pragma unroll
        for (int img = 0; img < BATCH; img++) {
            float l = smf[2 * img][0] + smf[2 * img + 1][0];
            float g = smf[2 * img][1] + smf[2 * img + 1][1];
            float mx = fmaxf(smf[2 * img][2], smf[2 * img + 1][2]);
            dl += l / mx;
            gl += g;
        }
        out[0] = dl / (float)(SS * BATCH);
        out[1] = gl / (float)(SS * BATCH);
    }
}

extern "C" void kernel_launch(void* const* d_in, const int* in_sizes, int n_in,
                              void* d_out, int out_size, void* d_ws, size_t ws_size,
                              hipStream_t stream) {
    const float* pred = (const float*)d_in[0];
    const float* ptl  = (const float*)d_in[1];
    const float* ori  = (const float*)d_in[2];
    float* out = (float*)d_out;
    int* wsi = (int*)d_ws;
    float* wsf = (float*)d_ws;

    k_points<<<1024, 256, 0, stream>>>(ptl, wsi);
    k_main<<<1024, 256, 0, stream>>>(pred, ori, wsi, wsf);
    k_final<<<1, 1024, 0, stream>>>(wsf, out);
}